// Round 1
// baseline (745.909 us; speedup 1.0000x reference)
//
#include <hip/hip_runtime.h>

#define NT 256

__device__ __forceinline__ float fast_tanh(float x) {
  float cl = fminf(fmaxf(x, -15.f), 15.f);
  float e = __builtin_amdgcn_exp2f(cl * 2.885390081777927f);  // exp(2x) = 2^(2*log2e*x)
  return (e - 1.f) * __builtin_amdgcn_rcpf(e + 1.f);
}

__device__ __forceinline__ unsigned int pack2_bf16(float a, float b) {
  unsigned int ua = __float_as_uint(a);
  unsigned int ub = __float_as_uint(b);
  ua = (ua + 0x7fffu + ((ua >> 16) & 1u)) >> 16;          // RNE to bf16, low half
  ub = (ub + 0x7fffu + ((ub >> 16) & 1u)) & 0xffff0000u;  // RNE to bf16, high half
  return ua | ub;
}

// One block = one molecule. Fully fused: d_hat built once into LDS (bf16),
// 3 message-passing iterations, MLP head + masked reduce.
__global__ __launch_bounds__(NT, 2) void mdtnn_fused(
    const int* __restrict__ Zg, const float* __restrict__ Dg,
    const int* __restrict__ sizesg, const float* __restrict__ embg,
    const float* __restrict__ dfwg, const float* __restrict__ dfbg,
    const float* __restrict__ cfwg, const float* __restrict__ cfbg,
    const float* __restrict__ fcwg, const float* __restrict__ w1g,
    const float* __restrict__ b1g, const float* __restrict__ w2g,
    const float* __restrict__ b2g, float* __restrict__ outg)
{
  const int b = blockIdx.x;
  const int tid = threadIdx.x;
  const int n = sizesg[b];            // 1..30
  const int njt = (n + 5) / 6;        // j-tiles of 6

  // cx[0] = C matrix [30][32], cx[1] = X1 [30][32]; phase A overlays dfwT here.
  __shared__ __align__(16) float cx[2][30][32];
  __shared__ __align__(16) float cfw_s[32][32];
  __shared__ __align__(16) float fcw_s[32][32];
  __shared__ __align__(16) float w1_s[32][16];
  // d_hat bf16: layout [i][hc(4)][j(30)][8 h] as int4 (=8 bf16), i-stride 121 int4 (pad for banks)
  __shared__ __align__(16) int4 dh2[30 * 121];
  __shared__ float dfb_s[32];
  __shared__ float cfb_s[32];
  __shared__ float b1_s[16];
  __shared__ float w2_s[16];
  __shared__ float bsum;

  float (*dfwT)[56] = reinterpret_cast<float (*)[56]>(&cx[0][0][0]);  // 1792 floats <= 1920

  // ---- stage weights into LDS ----
  for (int t = tid; t < 32 * 56; t += NT) {
    int h = t / 56, g = t - h * 56;
    dfwT[h][g] = (h < 30) ? dfwg[g * 30 + h] : 0.f;   // transpose df_w -> [h][g]
  }
  for (int t = tid; t < 1024; t += NT) {
    int h = t >> 5, k = t & 31;
    bool in = (h < 30) && (k < 30);
    cfw_s[h][k] = in ? cfwg[h * 30 + k] : 0.f;
    fcw_s[h][k] = in ? fcwg[h * 30 + k] : 0.f;
  }
  for (int t = tid; t < 512; t += NT) {
    int h = t >> 4, c = t & 15;
    w1_s[h][c] = ((h < 30) && (c < 15)) ? w1g[h * 15 + c] : 0.f;
  }
  if (tid < 32) {
    dfb_s[tid] = (tid < 30) ? dfbg[tid] : 0.f;
    cfb_s[tid] = (tid < 30) ? cfbg[tid] : 0.f;
  }
  if (tid < 16) {
    b1_s[tid] = (tid < 15) ? b1g[tid] : 0.f;
    w2_s[tid] = (tid < 15) ? w2g[tid] : 0.f;
  }
  if (tid == 0) bsum = 0.f;
  __syncthreads();

  // ---- phase A: d_hat[i][j][h] = D[b,i,j,:] @ df_w + df_b  (store bf16) ----
  {
    const int tasksA = n * njt * 4;   // (i, j-tile, h-tile of 8)
    for (int task = tid; task < tasksA; task += NT) {
      const int ht = task & 3;
      const int tmp = task >> 2;
      const int jt = tmp % njt;
      const int i = tmp / njt;
      const int j0 = jt * 6;
      const float* Dp = Dg + (((size_t)b * 30 + i) * 30 + j0) * 56;
      float acc[6][8];
      #pragma unroll
      for (int jj = 0; jj < 6; ++jj) {
        #pragma unroll
        for (int hh = 0; hh < 8; ++hh) acc[jj][hh] = 0.f;
      }
      #pragma unroll 2
      for (int gc = 0; gc < 14; ++gc) {
        float4 dj[6];
        #pragma unroll
        for (int jj = 0; jj < 6; ++jj)
          dj[jj] = *reinterpret_cast<const float4*>(Dp + jj * 56 + gc * 4);
        #pragma unroll
        for (int hh = 0; hh < 8; ++hh) {
          float4 w = *reinterpret_cast<const float4*>(&dfwT[ht * 8 + hh][gc * 4]);
          #pragma unroll
          for (int jj = 0; jj < 6; ++jj) {
            acc[jj][hh] = fmaf(dj[jj].x, w.x, acc[jj][hh]);
            acc[jj][hh] = fmaf(dj[jj].y, w.y, acc[jj][hh]);
            acc[jj][hh] = fmaf(dj[jj].z, w.z, acc[jj][hh]);
            acc[jj][hh] = fmaf(dj[jj].w, w.w, acc[jj][hh]);
          }
        }
      }
      #pragma unroll
      for (int jj = 0; jj < 6; ++jj) {
        int4 pk;
        pk.x = (int)pack2_bf16(acc[jj][0] + dfb_s[ht * 8 + 0], acc[jj][1] + dfb_s[ht * 8 + 1]);
        pk.y = (int)pack2_bf16(acc[jj][2] + dfb_s[ht * 8 + 2], acc[jj][3] + dfb_s[ht * 8 + 3]);
        pk.z = (int)pack2_bf16(acc[jj][4] + dfb_s[ht * 8 + 4], acc[jj][5] + dfb_s[ht * 8 + 5]);
        pk.w = (int)pack2_bf16(acc[jj][6] + dfb_s[ht * 8 + 6], acc[jj][7] + dfb_s[ht * 8 + 7]);
        dh2[i * 121 + ht * 30 + j0 + jj] = pk;
      }
    }
  }
  __syncthreads();

  // ---- init C from embeddings (overwrites dfwT overlay) ----
  for (int t = tid; t < n * 32; t += NT) {
    int i = t >> 5, h = t & 31;
    int z = Zg[b * 30 + i];
    cx[0][i][h] = (h < 30) ? embg[z * 30 + h] : 0.f;
  }
  __syncthreads();

  // ---- T = 3 message-passing iterations ----
  for (int it = 0; it < 3; ++it) {
    // X1 = C @ cf_w + cf_b  (pad cols give exact 0)
    for (int task = tid; task < n * 4; task += NT) {
      int i = task >> 2, kt = task & 3;
      float acc[8];
      #pragma unroll
      for (int kk = 0; kk < 8; ++kk) acc[kk] = 0.f;
      #pragma unroll
      for (int hc = 0; hc < 8; ++hc) {
        float4 c4 = *reinterpret_cast<const float4*>(&cx[0][i][hc * 4]);
        float cv[4] = {c4.x, c4.y, c4.z, c4.w};
        #pragma unroll
        for (int q = 0; q < 4; ++q) {
          float4 wa = *reinterpret_cast<const float4*>(&cfw_s[hc * 4 + q][kt * 8]);
          float4 wb = *reinterpret_cast<const float4*>(&cfw_s[hc * 4 + q][kt * 8 + 4]);
          acc[0] = fmaf(cv[q], wa.x, acc[0]);
          acc[1] = fmaf(cv[q], wa.y, acc[1]);
          acc[2] = fmaf(cv[q], wa.z, acc[2]);
          acc[3] = fmaf(cv[q], wa.w, acc[3]);
          acc[4] = fmaf(cv[q], wb.x, acc[4]);
          acc[5] = fmaf(cv[q], wb.y, acc[5]);
          acc[6] = fmaf(cv[q], wb.z, acc[6]);
          acc[7] = fmaf(cv[q], wb.w, acc[7]);
        }
      }
      #pragma unroll
      for (int kk = 0; kk < 8; ++kk)
        cx[1][i][kt * 8 + kk] = acc[kk] + cfb_s[kt * 8 + kk];
    }
    __syncthreads();

    // C[j] += sum_i tanh( (X1[i] ⊙ dh[i][j]) @ fc_w ); X1 is a snapshot, so
    // atomically updating C in place is race-free.
    const int tasksB = n * njt * 4;   // (i, j-tile of 6, k-tile of 8)
    for (int task = tid; task < tasksB; task += NT) {
      const int kt = task & 3;
      const int tmp = task >> 2;
      const int jt = tmp % njt;
      const int i = tmp / njt;
      const int j0 = jt * 6;
      float acc[6][8];
      #pragma unroll
      for (int jj = 0; jj < 6; ++jj) {
        #pragma unroll
        for (int kk = 0; kk < 8; ++kk) acc[jj][kk] = 0.f;
      }
      #pragma unroll 1
      for (int hc = 0; hc < 4; ++hc) {
        int4 dv[6];
        #pragma unroll
        for (int jj = 0; jj < 6; ++jj)
          dv[jj] = dh2[i * 121 + hc * 30 + j0 + jj];
        float4 xa = *reinterpret_cast<const float4*>(&cx[1][i][hc * 8]);
        float4 xb = *reinterpret_cast<const float4*>(&cx[1][i][hc * 8 + 4]);
        float xh[8] = {xa.x, xa.y, xa.z, xa.w, xb.x, xb.y, xb.z, xb.w};
        #pragma unroll
        for (int hh = 0; hh < 8; ++hh) {
          float4 wa = *reinterpret_cast<const float4*>(&fcw_s[hc * 8 + hh][kt * 8]);
          float4 wb = *reinterpret_cast<const float4*>(&fcw_s[hc * 8 + hh][kt * 8 + 4]);
          #pragma unroll
          for (int jj = 0; jj < 6; ++jj) {
            unsigned int u = reinterpret_cast<const unsigned int*>(&dv[jj])[hh >> 1];
            float d = (hh & 1) ? __uint_as_float(u & 0xffff0000u)
                               : __uint_as_float(u << 16);
            float a = d * xh[hh];
            acc[jj][0] = fmaf(a, wa.x, acc[jj][0]);
            acc[jj][1] = fmaf(a, wa.y, acc[jj][1]);
            acc[jj][2] = fmaf(a, wa.z, acc[jj][2]);
            acc[jj][3] = fmaf(a, wa.w, acc[jj][3]);
            acc[jj][4] = fmaf(a, wb.x, acc[jj][4]);
            acc[jj][5] = fmaf(a, wb.y, acc[jj][5]);
            acc[jj][6] = fmaf(a, wb.z, acc[jj][6]);
            acc[jj][7] = fmaf(a, wb.w, acc[jj][7]);
          }
        }
      }
      #pragma unroll
      for (int jj = 0; jj < 6; ++jj) {
        #pragma unroll
        for (int kk = 0; kk < 8; ++kk)
          atomicAdd(&cx[0][j0 + jj][kt * 8 + kk], fast_tanh(acc[jj][kk]));
      }
    }
    __syncthreads();
  }

  // ---- MLP head + masked reduce: out[b] = sum_{j<n} (tanh(C[j]@w1+b1)@w2 + b2) ----
  for (int t = tid; t < n * 16; t += NT) {
    int j = t >> 4, c = t & 15;
    if (c < 15) {
      float acc = 0.f;
      #pragma unroll
      for (int hc = 0; hc < 8; ++hc) {
        float4 c4 = *reinterpret_cast<const float4*>(&cx[0][j][hc * 4]);
        acc = fmaf(c4.x, w1_s[hc * 4 + 0][c], acc);
        acc = fmaf(c4.y, w1_s[hc * 4 + 1][c], acc);
        acc = fmaf(c4.z, w1_s[hc * 4 + 2][c], acc);
        acc = fmaf(c4.w, w1_s[hc * 4 + 3][c], acc);
      }
      atomicAdd(&bsum, fast_tanh(acc + b1_s[c]) * w2_s[c]);
    }
  }
  __syncthreads();
  if (tid == 0) outg[b] = bsum + (float)n * b2g[0];
}

extern "C" void kernel_launch(void* const* d_in, const int* in_sizes, int n_in,
                              void* d_out, int out_size, void* d_ws, size_t ws_size,
                              hipStream_t stream) {
  (void)in_sizes; (void)n_in; (void)d_ws; (void)ws_size;
  const int*   Z   = (const int*)d_in[0];
  const float* D   = (const float*)d_in[1];
  const int*   sz  = (const int*)d_in[2];
  const float* emb = (const float*)d_in[3];
  const float* dfw = (const float*)d_in[4];
  const float* dfb = (const float*)d_in[5];
  const float* cfw = (const float*)d_in[6];
  const float* cfb = (const float*)d_in[7];
  const float* fcw = (const float*)d_in[8];
  const float* w1  = (const float*)d_in[9];
  const float* b1  = (const float*)d_in[10];
  const float* w2  = (const float*)d_in[11];
  const float* b2  = (const float*)d_in[12];
  float* out = (float*)d_out;
  const int B = out_size;  // 2048 molecules, one block each
  mdtnn_fused<<<dim3(B), dim3(NT), 0, stream>>>(Z, D, sz, emb, dfw, dfb, cfw, cfb,
                                                fcw, w1, b1, w2, b2, out);
}